// Round 4
// baseline (1635.269 us; speedup 1.0000x reference)
//
#include <hip/hip_runtime.h>

// Problem shape
#define M_TOK 8192
#define N_OUT 11008
#define K_IN  4096
#define NGRP  32      // K_IN / 128
#define RANK  32
#define NPROT 64

typedef _Float16 f16;
typedef _Float16 f16x8 __attribute__((ext_vector_type(8)));
typedef _Float16 f16x4 __attribute__((ext_vector_type(4)));
typedef float    f32x4 __attribute__((ext_vector_type(4)));

// ---------------- helpers ----------------
__device__ __forceinline__ void async16(const f16* g, f16* l) {
  // global -> LDS direct copy, 16 B per lane; LDS dest = wave-uniform base + lane*16
  __builtin_amdgcn_global_load_lds(
      (const __attribute__((address_space(1))) void*)g,
      (__attribute__((address_space(3))) void*)l, 16, 0, 0);
}

// ---------------- 1) convert fp32 -> f16 (vectorized, 4 elem/thread) ----------------
__global__ __launch_bounds__(256) void k_convert4(const float* __restrict__ in,
                                                  f16* __restrict__ outp) {
  const int i = (blockIdx.x * 256 + threadIdx.x) * 4;
  const float4 v = *reinterpret_cast<const float4*>(in + i);
  f16x4 h;
  h[0] = (f16)v.x; h[1] = (f16)v.y; h[2] = (f16)v.z; h[3] = (f16)v.w;
  *reinterpret_cast<f16x4*>(outp + i) = h;
}

// ---------------- 2) V[32][4096] fp32 -> Vt_h[4096][32] f16 ----------------
__global__ __launch_bounds__(256) void k_convert_vt(const float* __restrict__ V,
                                                    f16* __restrict__ vt) {
  const int c = blockIdx.x * 256 + threadIdx.x;  // 0..4095
  f16 tmp[32];
#pragma unroll
  for (int r = 0; r < 32; ++r) tmp[r] = (f16)V[r * K_IN + c];
#pragma unroll
  for (int j = 0; j < 4; ++j)
    *reinterpret_cast<f16x8*>(vt + (size_t)c * 32 + j * 8) =
        *reinterpret_cast<const f16x8*>(&tmp[j * 8]);
}

// ---------------- 3) UV (rank-32 MFMA) + int4 dequant + awq undo -> W_f16 ----------------
// grid = (K_IN/128, N_OUT/128); one 128x128 tile of W per block, 4 waves 2x2.
// K-tile (128) == GROUP_SIZE so the quant group is block-uniform.
__global__ __launch_bounds__(256) void k_uv_dequant(
    const f16* __restrict__ Uh,       // [N_OUT][32]
    const f16* __restrict__ Vth,      // [K_IN][32]  (V transposed)
    const int* __restrict__ qw,       // [N_OUT][K_IN]
    const float* __restrict__ scales, // [N_OUT][NGRP]
    const float* __restrict__ zeros,  // [N_OUT][NGRP]
    const float* __restrict__ awq,    // [K_IN]
    f16* __restrict__ Wh)             // [N_OUT][K_IN]
{
  const int k0 = blockIdx.x * 128;
  const int n0 = blockIdx.y * 128;
  const int lane = threadIdx.x & 63, wid = threadIdx.x >> 6;
  const int wr = wid >> 1, wc = wid & 1;
  const int r16 = lane & 15;
  const int kh  = (lane >> 4) * 8;   // k-offset within rank-32

  f32x4 acc[4][4] = {};
  f16x8 a[4], b[4];
#pragma unroll
  for (int m = 0; m < 4; ++m)
    a[m] = *reinterpret_cast<const f16x8*>(Uh + (size_t)(n0 + wr * 64 + m * 16 + r16) * 32 + kh);
#pragma unroll
  for (int n = 0; n < 4; ++n)
    b[n] = *reinterpret_cast<const f16x8*>(Vth + (size_t)(k0 + wc * 64 + n * 16 + r16) * 32 + kh);
#pragma unroll
  for (int m = 0; m < 4; ++m)
#pragma unroll
    for (int n = 0; n < 4; ++n)
      acc[m][n] = __builtin_amdgcn_mfma_f32_16x16x32_f16(a[m], b[n], acc[m][n], 0, 0, 0);

  const int g = k0 >> 7;  // uniform quant group for the whole tile
  float aw[4];
#pragma unroll
  for (int n = 0; n < 4; ++n) aw[n] = awq[k0 + wc * 64 + n * 16 + r16];

#pragma unroll
  for (int m = 0; m < 4; ++m) {
#pragma unroll
    for (int jj = 0; jj < 4; ++jj) {
      const int row = n0 + wr * 64 + m * 16 + (lane >> 4) * 4 + jj;
      const float zp = zeros[row * NGRP + g];
      const float sc = scales[row * NGRP + g];
#pragma unroll
      for (int n = 0; n < 4; ++n) {
        const int col = k0 + wc * 64 + n * 16 + r16;
        const float q = (float)qw[(size_t)row * K_IN + col];
        const float w = (q - zp) * sc / aw[n] + acc[m][n][jj];
        Wh[(size_t)row * K_IN + col] = (f16)w;
      }
    }
  }
}

// ---------------- 4) protected columns (serial in p => last-wins on duplicates) ----------------
__global__ __launch_bounds__(256) void k_protect(const int* __restrict__ idx,
                                                 const float* __restrict__ pv,
                                                 f16* __restrict__ Wh) {
  const int n = blockIdx.x * 256 + threadIdx.x;  // 0..11007 (grid exact)
#pragma unroll 1
  for (int p = 0; p < NPROT; ++p) {
    const int col = idx[p];  // uniform -> scalar load
    Wh[(size_t)n * K_IN + col] = (f16)pv[(size_t)n * NPROT + p];
  }
}

// ---------------- 5) C[M,N] = Xh[M,K] @ Wh[N,K]^T   (f16 MFMA, fp32 out) ----------------
// 128x128 tile, BK=64, 256 threads = 4 waves (2x2), m97 structure:
// global_load_lds width-16 staging, single LDS buffer, 2 barriers / K-step.
#define TM 128
#define TN 128
#define TK 64

__global__ __launch_bounds__(256) void k_gemm(const f16* __restrict__ Xh,
                                              const f16* __restrict__ Wh,
                                              float* __restrict__ outp) {
  __shared__ f16 sA[TM][TK];
  __shared__ f16 sB[TN][TK];

  // bijective XCD swizzle: 5504 blocks = 8 * 688
  const int orig = blockIdx.x;
  const int swz  = (orig & 7) * (5504 / 8) + (orig >> 3);
  const int bx = swz % 86;          // n-tile
  const int by = swz / 86;          // m-tile
  const int m0 = by * TM, n0 = bx * TN;

  const int tid = threadIdx.x, lane = tid & 63, wid = tid >> 6;
  const int wr = wid >> 1, wc = wid & 1;

  // staging: 16 chunks of 1024 B per tile; wave w owns chunks w*4 .. w*4+3
  const int srow = lane >> 3;          // row within 8-row chunk
  const int scol = (lane & 7) * 8;     // halves within row
  const f16* gA[4];
  const f16* gB[4];
  f16* lA[4];
  f16* lB[4];
#pragma unroll
  for (int r = 0; r < 4; ++r) {
    const int chunk = wid * 4 + r;
    gA[r] = Xh + (size_t)(m0 + chunk * 8 + srow) * K_IN + scol;
    gB[r] = Wh + (size_t)(n0 + chunk * 8 + srow) * K_IN + scol;
    lA[r] = &sA[0][0] + chunk * 512;   // 512 halves = 8 rows * 64
    lB[r] = &sB[0][0] + chunk * 512;
  }

  const int r16 = lane & 15;
  const int kh  = (lane >> 4) * 8;
  f32x4 acc[4][4] = {};

  for (int kt = 0; kt < K_IN / TK; ++kt) {
    __syncthreads();  // previous compute done; LDS reusable
#pragma unroll
    for (int r = 0; r < 4; ++r) {
      async16(gA[r] + kt * TK, lA[r]);
      async16(gB[r] + kt * TK, lB[r]);
    }
    asm volatile("s_waitcnt vmcnt(0)" ::: "memory");
    __syncthreads();

#pragma unroll
    for (int kk = 0; kk < 2; ++kk) {
      f16x8 af[4], bf[4];
#pragma unroll
      for (int m = 0; m < 4; ++m)
        af[m] = *reinterpret_cast<const f16x8*>(&sA[wr * 64 + m * 16 + r16][kk * 32 + kh]);
#pragma unroll
      for (int n = 0; n < 4; ++n)
        bf[n] = *reinterpret_cast<const f16x8*>(&sB[wc * 64 + n * 16 + r16][kk * 32 + kh]);
#pragma unroll
      for (int m = 0; m < 4; ++m)
#pragma unroll
        for (int n = 0; n < 4; ++n)
          acc[m][n] = __builtin_amdgcn_mfma_f32_16x16x32_f16(af[m], bf[n], acc[m][n], 0, 0, 0);
    }
  }

  // epilogue: C/D layout col=lane&15, row=(lane>>4)*4+reg  [m89-verified]
  const int crow = (lane >> 4) * 4;
#pragma unroll
  for (int m = 0; m < 4; ++m)
#pragma unroll
    for (int n = 0; n < 4; ++n)
#pragma unroll
      for (int jj = 0; jj < 4; ++jj)
        outp[(size_t)(m0 + wr * 64 + m * 16 + crow + jj) * N_OUT +
             (n0 + wc * 64 + n * 16 + r16)] = acc[m][n][jj];
}

// ---------------- launch ----------------
extern "C" void kernel_launch(void* const* d_in, const int* in_sizes, int n_in,
                              void* d_out, int out_size, void* d_ws, size_t ws_size,
                              hipStream_t stream) {
  const float* x      = (const float*)d_in[0];
  const int*   qw     = (const int*)d_in[1];
  const float* scales = (const float*)d_in[2];
  const float* zeros  = (const float*)d_in[3];
  const float* awq    = (const float*)d_in[4];
  const int*   pidx   = (const int*)d_in[5];
  const float* pval   = (const float*)d_in[6];
  const float* U      = (const float*)d_in[7];
  const float* V      = (const float*)d_in[8];
  float* outp = (float*)d_out;

  char* ws = (char*)d_ws;
  // layout: Wh [0, 90,177,536) ; Xh [90,177,536, 157,286,400)
  // Uh/Vth live at the start of the Xh region and are dead before k_convert4(x) runs.
  f16* Wh  = (f16*)ws;
  f16* Uh  = (f16*)(ws + 90177536);
  f16* Vth = (f16*)(ws + 90177536 + 704512);
  f16* Xh  = (f16*)(ws + 90177536);

  // U -> f16 : 11008*32 = 352256 elems = 344 blocks * 1024
  k_convert4<<<344, 256, 0, stream>>>(U, Uh);
  // V -> f16 transposed [4096][32]
  k_convert_vt<<<16, 256, 0, stream>>>(V, Vth);
  // W_f16 = dequant(q)*scale / awq + U@V   (protected cols applied next)
  k_uv_dequant<<<dim3(K_IN / 128, N_OUT / 128), 256, 0, stream>>>(
      Uh, Vth, qw, scales, zeros, awq, Wh);
  // protected full-precision columns (last, replacing everything)
  k_protect<<<N_OUT / 256, 256, 0, stream>>>(pidx, pval, Wh);
  // x -> f16 (overwrites Uh/Vth region, which is dead now)
  k_convert4<<<(M_TOK * K_IN) / 1024, 256, 0, stream>>>(x, Xh);
  // main GEMM
  k_gemm<<<(M_TOK / TM) * (N_OUT / TN), 256, 0, stream>>>(Xh, Wh, outp);
}